// Round 1
// 265.701 us; speedup vs baseline: 1.0633x; 1.0633x over previous
//
#include <hip/hip_runtime.h>

// Problem: M=65536, K=512, N=512
//   x_scale = max(|x|)/127 (>= 1e-5); x_int8 = clip(rint(x/x_scale));
//   out = (x_int8 @ W^T).f32 * (x_scale * wscale[n])
//
// R6: fuse quant + gemm into one strip-persistent kernel.
//   k1 (unchanged, proven): 4096-chunk absmax partials + weight repack.
//   k2 (new, 512 blocks = 2/CU): each block owns a 128-row M-strip:
//     - self-reduces the 4096 partials (16 KB L2 broadcast) -> scale
//     - quantizes its strip from L3-hot x into XOR-swizzled A-LDS (64 KB)
//     - pulls A fragments into 64 VGPRs, then REUSES the same LDS buffer
//       to stage B tiles (4x 64 KB, fragment order) for the 4 N-tiles.
//   Eliminates the x8 HBM round-trip (64 MB) and one kernel launch.
//   A-LDS swizzle: byte ^= (row&7)<<4 (stride-512 row-major reads are a
//   32-way bank conflict otherwise; swizzle -> 2-way = free).

#define M_DIM 65536
#define K_DIM 512
#define N_DIM 512
#define EPSF  1e-5f

typedef int int32x4 __attribute__((ext_vector_type(4)));

// ---- ws layout (bytes) ----
#define WS_PART   256                       // 4096 float partials (16 KB)
#define WS_WPACK  32768                     // packed int8 weight (256 KB)

__device__ inline unsigned int pack_w4(int4 v) {
    return (v.x & 0xff) | ((v.y & 0xff) << 8) |
           ((v.z & 0xff) << 16) | ((unsigned)v.w << 24);
}

// quantize 4 floats -> 4 packed int8 (RNE magic constant; no clamp needed
// since |x*inv| <= ~127.00002).
__device__ inline unsigned int quantpack4(float4 f, float inv) {
    const float C = 12582912.0f;  // 1.5 * 2^23
    unsigned int u0 = __float_as_uint(fmaf(f.x, inv, C));
    unsigned int u1 = __float_as_uint(fmaf(f.y, inv, C));
    unsigned int u2 = __float_as_uint(fmaf(f.z, inv, C));
    unsigned int u3 = __float_as_uint(fmaf(f.w, inv, C));
    unsigned int lo = __builtin_amdgcn_perm(u1, u0, 0x0C0C0400u);
    unsigned int hi = __builtin_amdgcn_perm(u3, u2, 0x04000C0Cu);
    return lo | hi;
}

// ---------------- Kernel 1: absmax partials + weight repack (fused grid) ----
// blocks 0..4095: partial absmax of a contiguous 32 KB chunk of x.
// blocks 4096..4159: repack the 1 MB int32 weight into 256 KB int8.
__global__ void absmax1_pack_kernel(const float* __restrict__ x,
                                    const int* __restrict__ wi,
                                    float* __restrict__ partials,
                                    unsigned int* __restrict__ wp) {
    const int b = blockIdx.x;
    const int t = threadIdx.x;
    if (b < 4096) {
        __shared__ float red[4];
        const float4* x4 = (const float4*)x;
        const int base = b * 2048;               // float4 units (32 KB chunk)
        float m = 0.0f;
        #pragma unroll
        for (int j = 0; j < 8; ++j) {
            float4 v = x4[base + j * 256 + t];
            m = fmaxf(m, fmaxf(fmaxf(fabsf(v.x), fabsf(v.y)),
                               fmaxf(fabsf(v.z), fabsf(v.w))));
        }
        #pragma unroll
        for (int off = 32; off > 0; off >>= 1)
            m = fmaxf(m, __shfl_xor(m, off));
        if ((t & 63) == 0) red[t >> 6] = m;
        __syncthreads();
        if (t == 0)
            partials[b] = fmaxf(fmaxf(red[0], red[1]), fmaxf(red[2], red[3]));
    } else {
        const int bb = b - 4096;
        #pragma unroll
        for (int j = 0; j < 4; ++j) {
            int d = bb * 1024 + j * 256 + t;     // packed dword index
            wp[d] = pack_w4(((const int4*)wi)[d]);
        }
    }
}

// ---------------- Kernel 2: fused quant + int8 GEMM + dequant --------------
// 512 blocks x 256 threads (4 waves), 2 blocks/CU. Block owns M-strip
// [128*blockIdx, +128). One 64 KB LDS buffer, time-shared: A (swizzled int8
// strip) -> A frags to regs -> B tile staging per N-tile.
__global__ __launch_bounds__(256, 2) void fused_quant_gemm_kernel(
    const float* __restrict__ x, const signed char* __restrict__ w,
    const float* __restrict__ wscale, const float* __restrict__ partials,
    float* __restrict__ out) {
    __shared__ __attribute__((aligned(16))) signed char Lds[64 * 1024];
    __shared__ float red[4];

    const int t    = threadIdx.x;
    const int wave = t >> 6;
    const int lane = t & 63;
    const int quad = lane >> 4;
    const int l16  = lane & 15;
    const int m0   = blockIdx.x * 128;

    // ---- reduce 4096 partials -> scale (16 KB, L2 broadcast) ----
    float m = 0.0f;
    {
        const float4* p4 = (const float4*)partials;
        #pragma unroll
        for (int j = 0; j < 4; ++j) {
            float4 v = p4[t + j * 256];
            m = fmaxf(m, fmaxf(fmaxf(v.x, v.y), fmaxf(v.z, v.w)));
        }
        #pragma unroll
        for (int off = 32; off > 0; off >>= 1)
            m = fmaxf(m, __shfl_xor(m, off));
        if (lane == 0) red[wave] = m;
    }
    __syncthreads();
    const float mx  = fmaxf(fmaxf(red[0], red[1]), fmaxf(red[2], red[3]));
    const float s   = fmaxf(mx / 127.0f, EPSF);
    const float inv = 1.0f / s;
    __syncthreads();                 // red[] dead; Lds writes start below

    // ---- quantize own strip (256 KB fp32, L3-hot) into swizzled A-LDS ----
    // thread t, iter j: 4 consecutive float4 = 16 floats = one 16 B LDS slot
    // at (row = j*8 + t/32, bytecol = (t&31)*16), byte ^= (row&7)<<4.
    {
        const float4* xs = (const float4*)(x + (size_t)m0 * K_DIM);
        const int rsub = t >> 5;
        const int csub = (t & 31) * 16;
        #pragma unroll
        for (int j = 0; j < 16; ++j) {
            const int fi = j * 1024 + t * 4;     // float4 index in strip
            float4 v0 = xs[fi + 0];
            float4 v1 = xs[fi + 1];
            float4 v2 = xs[fi + 2];
            float4 v3 = xs[fi + 3];
            int32x4 p;
            p.x = (int)quantpack4(v0, inv);
            p.y = (int)quantpack4(v1, inv);
            p.z = (int)quantpack4(v2, inv);
            p.w = (int)quantpack4(v3, inv);
            const int row  = j * 8 + rsub;
            const int addr = (row * 512 + csub) ^ ((row & 7) << 4);
            *(int32x4*)(Lds + addr) = p;
        }
    }
    __syncthreads();

    // ---- A fragments -> registers (64 VGPRs), then LDS is free for B ----
    int32x4 a0[8], a1[8];
    {
        const int r0 = wave * 32 + l16;
        const int r1 = r0 + 16;
        #pragma unroll
        for (int k = 0; k < 8; ++k) {
            const int c = quad * 16 + k * 64;
            a0[k] = *(const int32x4*)(Lds + ((r0 * 512 + c) ^ ((r0 & 7) << 4)));
            a1[k] = *(const int32x4*)(Lds + ((r1 * 512 + c) ^ ((r1 & 7) << 4)));
        }
    }
    __syncthreads();   // every wave done reading A before B staging

    const int mw = m0 + wave * 32;

    for (int bx = 0; bx < 4; ++bx) {
        const int n0 = bx * 128;

        // stage B tile (64 KB) in fragment order [c=k/64][t][lane][16B]
        #pragma unroll
        for (int cc = 0; cc < 2; ++cc) {
            int c = wave * 2 + cc;
            #pragma unroll
            for (int tt = 0; tt < 8; ++tt) {
                const signed char* g = w + (long)(n0 + tt * 16 + l16) * K_DIM
                                         + c * 64 + quad * 16;
                __builtin_amdgcn_global_load_lds(
                    (const __attribute__((address_space(1))) unsigned int*)g,
                    (__attribute__((address_space(3))) unsigned int*)(Lds + (c * 8 + tt) * 1024),
                    16, 0, 0);
            }
        }
        __syncthreads();

        int32x4 acc0[8] = {};
        int32x4 acc1[8] = {};
        #pragma unroll
        for (int k = 0; k < 8; ++k) {
            const signed char* bbase = Lds + k * 8192 + lane * 16;
            #pragma unroll
            for (int tt = 0; tt < 8; ++tt) {
                int32x4 b = *(const int32x4*)(bbase + tt * 1024);
                acc0[tt] = __builtin_amdgcn_mfma_i32_16x16x64_i8(a0[k], b, acc0[tt], 0, 0, 0);
                acc1[tt] = __builtin_amdgcn_mfma_i32_16x16x64_i8(a1[k], b, acc1[tt], 0, 0, 0);
            }
        }

        // epilogue for this N-tile
        #pragma unroll
        for (int tt = 0; tt < 8; ++tt) {
            int n = n0 + tt * 16 + l16;
            float c = s * wscale[n];
            float* o0 = out + (long)(mw + quad * 4) * N_DIM + n;
            float* o1 = o0 + (long)16 * N_DIM;
            #pragma unroll
            for (int r = 0; r < 4; ++r) {
                o0[(long)r * N_DIM] = (float)acc0[tt][r] * c;
                o1[(long)r * N_DIM] = (float)acc1[tt][r] * c;
            }
        }
        if (bx < 3) __syncthreads();   // Lds reads/stores done before restage
    }
}

extern "C" void kernel_launch(void* const* d_in, const int* in_sizes, int n_in,
                              void* d_out, int out_size, void* d_ws, size_t ws_size,
                              hipStream_t stream) {
    const float* x   = (const float*)d_in[0];
    const int*   wi  = (const int*)d_in[1];    // int8 values stored as int32
    const float* sc  = (const float*)d_in[2];
    float*       out = (float*)d_out;

    float*        partials = (float*)((char*)d_ws + WS_PART);
    unsigned int* wp       = (unsigned int*)((char*)d_ws + WS_WPACK);
    const signed char* w8  = (const signed char*)wp;

    absmax1_pack_kernel<<<4160, 256, 0, stream>>>(x, wi, partials, wp);
    fused_quant_gemm_kernel<<<512, 256, 0, stream>>>(x, w8, sc, partials, out);
}